// Round 1
// baseline (599.649 us; speedup 1.0000x reference)
//
#include <hip/hip_runtime.h>

// SpectralConv1d: out[b,s,o,k,c] = complex matmul over i, per mode k.
//   out_r = sum_i xr*wr - xi*wi ; out_i = sum_i xr*wi + xi*wr
// x: (8,2048,32,64,2) f32; w: (32,32,64,2) f32; out: (8,2048,32,64,2) f32.
// Memory-bound: 537 MB total traffic -> ~85us floor @6.3TB/s.

constexpr int D_IN  = 32;
constexpr int D_OUT = 32;
constexpr int KMAX  = 64;
constexpr int NPOS  = 8 * 2048;   // b*s flattened
constexpr int POSB  = 8;          // positions per block
constexpr int OT    = 4;          // outputs (o) per thread
constexpr int THREADS = 512;      // 64 k-lanes x 8 o-groups

__global__ __launch_bounds__(THREADS, 4)
void spectral_conv1d_kernel(const float2* __restrict__ x,
                            const float2* __restrict__ w,
                            float2* __restrict__ out) {
    const int tid = threadIdx.x;
    const int k   = tid & (KMAX - 1);   // lanes 0..63 -> coalesced over k
    const int og  = tid >> 6;           // 0..7
    const int o0  = og * OT;            // this thread's first output channel
    const long posBase = (long)blockIdx.x * POSB;

    // float2 element index: x[(pos*32 + i)*64 + k], w[(o*32 + i)*64 + k]
    const float2* xb = x + posBase * (D_IN * KMAX) + k;
    const float2* wb = w + (long)o0 * (D_IN * KMAX) + k;

    float2 acc[POSB][OT];
    #pragma unroll
    for (int p = 0; p < POSB; ++p)
        #pragma unroll
        for (int j = 0; j < OT; ++j) acc[p][j] = make_float2(0.f, 0.f);

    for (int i = 0; i < D_IN; ++i) {
        float2 wv[OT];
        #pragma unroll
        for (int j = 0; j < OT; ++j)
            wv[j] = wb[(j * D_IN + i) * KMAX];   // o-stride = 32*64 float2

        #pragma unroll
        for (int p = 0; p < POSB; ++p) {
            float2 xv = xb[(p * D_IN + i) * KMAX];
            #pragma unroll
            for (int j = 0; j < OT; ++j) {
                acc[p][j].x = fmaf(xv.x,  wv[j].x, acc[p][j].x);
                acc[p][j].x = fmaf(-xv.y, wv[j].y, acc[p][j].x);
                acc[p][j].y = fmaf(xv.x,  wv[j].y, acc[p][j].y);
                acc[p][j].y = fmaf(xv.y,  wv[j].x, acc[p][j].y);
            }
        }
    }

    float2* ob = out + posBase * (D_OUT * KMAX) + k;
    #pragma unroll
    for (int p = 0; p < POSB; ++p)
        #pragma unroll
        for (int j = 0; j < OT; ++j)
            ob[((long)p * D_OUT + o0 + j) * KMAX] = acc[p][j];
}

extern "C" void kernel_launch(void* const* d_in, const int* in_sizes, int n_in,
                              void* d_out, int out_size, void* d_ws, size_t ws_size,
                              hipStream_t stream) {
    const float2* x = (const float2*)d_in[0];
    const float2* w = (const float2*)d_in[1];
    float2* out     = (float2*)d_out;

    dim3 grid(NPOS / POSB);   // 2048 blocks
    spectral_conv1d_kernel<<<grid, THREADS, 0, stream>>>(x, w, out);
}